// Round 2
// baseline (443.359 us; speedup 1.0000x reference)
//
#include <hip/hip_runtime.h>

// GGNN on MI355X. N=100000 nodes, E=1000000 edges, H=M=64, C=16.
// bf16 MFMA (16x16x32) for all three matmuls; fp32 atomics for scatter-add;
// fp32 elementwise for GRU gates and the h blend.
// R1 post-mortem: absmax 1.53 traced to edge_types dtype — harness passes
// bool as int32 ("integer -> const int*"); uchar read got padding bytes for
// 75% of edges. Fix: runtime dtype detector (k_det) + byte-indexed read.
// ws layout: [agg f32 N*64 | feat_bf16 N*64 | weights_bf16 33792 | flag int]

typedef __bf16 bf16x8 __attribute__((ext_vector_type(8)));
typedef float  f32x4  __attribute__((ext_vector_type(4)));

#define MFMA16 __builtin_amdgcn_mfma_f32_16x16x32_bf16

__device__ __forceinline__ float sigmoidf_(float x) {
    return 1.0f / (1.0f + __expf(-x));
}

// ---- detect edge_types storage: flag=1 if 1-byte (bool/int8), 0 if int32 ----
// Scans first 64KB (buffer is >=1MB under either interpretation). For int32
// 0/1 data every byte at i%4!=0 is zero; for random bools ~49k of them are 1.
__global__ __launch_bounds__(256) void k_det(const unsigned char* __restrict__ et,
                                             int* __restrict__ flag) {
    int tid = threadIdx.x;
    if (tid == 0) *flag = 0;
    __syncthreads();
    int found = 0;
    for (int i = tid; i < 65536; i += 256)
        if ((i & 3) != 0 && et[i] != 0) found = 1;
    if (__any(found) && (threadIdx.x & 63) == 0) atomicOr(flag, 1);
}

// ---- prep: convert features f32 -> bf16, zero agg (same element count) ----
__global__ __launch_bounds__(256) void k_prep(const float* __restrict__ feat,
                                              __bf16* __restrict__ featb,
                                              float* __restrict__ agg, long n) {
    long i = ((long)blockIdx.x * 256 + threadIdx.x) * 4;
    if (i >= n) return;
    f32x4 v = *(const f32x4*)(feat + i);
    union { __bf16 e[4]; unsigned long long u; } o;
#pragma unroll
    for (int j = 0; j < 4; j++) o.e[j] = (__bf16)v[j];
    *(unsigned long long*)(featb + i) = o.u;
    f32x4 z = {0.f, 0.f, 0.f, 0.f};
    *(f32x4*)(agg + i) = z;
}

// ---- convert all weight matrices to bf16, concatenated ----
// layout in wb: W0[4096] W1[4096] W_ih[12288] W_hh[12288] W_out[1024]
__global__ __launch_bounds__(256) void k_cvtw(const float* __restrict__ w0,
                                              const float* __restrict__ w1,
                                              const float* __restrict__ wih,
                                              const float* __restrict__ whh,
                                              const float* __restrict__ wout,
                                              __bf16* __restrict__ wb) {
    int i = blockIdx.x * 256 + threadIdx.x;
    float v;
    if      (i < 4096)  v = w0[i];
    else if (i < 8192)  v = w1[i - 4096];
    else if (i < 20480) v = wih[i - 8192];
    else if (i < 32768) v = whh[i - 20480];
    else if (i < 33792) v = wout[i - 32768];
    else return;
    wb[i] = (__bf16)v;
}

// ---- edge kernel: msg = x @ Wsel^T + bsel, atomic scatter into agg ----
// One wave = 16 edges. A-frag rows = gathered feature rows (bf16, direct
// global 16B granules). B-frags = W0/W1 rows held in VGPRs (loaded once).
// D layout: lane holds (edge = quad*4+reg, m = nb*16 + (lane&15)).
__global__ __launch_bounds__(256) void k_edge(const __bf16* __restrict__ featb,
                                              const int* __restrict__ src,
                                              const int* __restrict__ dst,
                                              const unsigned char* __restrict__ etype,
                                              const int* __restrict__ flag,
                                              const __bf16* __restrict__ w0b,
                                              const __bf16* __restrict__ w1b,
                                              const float* __restrict__ b0,
                                              const float* __restrict__ b1,
                                              float* __restrict__ agg, int E) {
    int tid  = threadIdx.x;
    int lane = tid & 63, wave = tid >> 6;
    int L = lane & 15, q = lane >> 4;

    // byte stride over etype: 1 if bool/int8, 4 if int32 (LSB byte = value)
    int eshift = (*flag) ? 0 : 2;

    // B-frags for both weight types: B[n=nb*16+L][k=ch*32+q*8+j]
    bf16x8 Bw0[4][2], Bw1[4][2];
#pragma unroll
    for (int nb = 0; nb < 4; nb++)
#pragma unroll
        for (int ch = 0; ch < 2; ch++) {
            int off = (nb * 16 + L) * 64 + ch * 32 + q * 8;
            Bw0[nb][ch] = *(const bf16x8*)(w0b + off);
            Bw1[nb][ch] = *(const bf16x8*)(w1b + off);
        }
    float bs0[4], bs1[4];
#pragma unroll
    for (int nb = 0; nb < 4; nb++) {
        bs0[nb] = b0[nb * 16 + L];
        bs1[nb] = b1[nb * 16 + L];
    }

    int e0 = (blockIdx.x * 4 + wave) * 16;
    if (e0 >= E) return;

    // A-frag: row m = edge e0+L, k = ch*32 + q*8 + j
    int sA = src[e0 + L];
    const __bf16* xr = featb + (long)sA * 64;
    bf16x8 A0 = *(const bf16x8*)(xr + q * 8);
    bf16x8 A1 = *(const bf16x8*)(xr + 32 + q * 8);

    f32x4 zz = {0.f, 0.f, 0.f, 0.f};
    f32x4 acc0[4], acc1[4];
#pragma unroll
    for (int nb = 0; nb < 4; nb++) { acc0[nb] = zz; acc1[nb] = zz; }

#pragma unroll
    for (int nb = 0; nb < 4; nb++) {
        acc0[nb] = MFMA16(A0, Bw0[nb][0], acc0[nb], 0, 0, 0);
        acc0[nb] = MFMA16(A1, Bw0[nb][1], acc0[nb], 0, 0, 0);
        acc1[nb] = MFMA16(A0, Bw1[nb][0], acc1[nb], 0, 0, 0);
        acc1[nb] = MFMA16(A1, Bw1[nb][1], acc1[nb], 0, 0, 0);
    }

    // epilogue: select per edge type, add bias, atomic scatter
#pragma unroll
    for (int r = 0; r < 4; r++) {
        int er = e0 + q * 4 + r;
        int d  = dst[er];
        bool t = etype[(size_t)er << eshift] != 0;  // True -> W0/b0 path (m0)
        float* drow = agg + (long)d * 64 + L;
#pragma unroll
        for (int nb = 0; nb < 4; nb++) {
            float v = t ? (acc0[nb][r] + bs0[nb]) : (acc1[nb][r] + bs1[nb]);
            atomicAdd(drow + nb * 16, v);
        }
    }
}

// ---- GRU + classifier: one wave = 16 nodes ----
__global__ __launch_bounds__(256) void k_gru(const float* __restrict__ agg,
                                             const float* __restrict__ feat,
                                             const __bf16* __restrict__ featb,
                                             const __bf16* __restrict__ wihb,
                                             const __bf16* __restrict__ whhb,
                                             const float* __restrict__ bih,
                                             const float* __restrict__ bhh,
                                             const __bf16* __restrict__ woutb,
                                             const float* __restrict__ bout,
                                             float* __restrict__ out, int N) {
    __shared__ __bf16 sH[4][16][80];  // per-wave h tile, stride 80 (bank spread)
    int tid  = threadIdx.x;
    int lane = tid & 63, wave = tid >> 6;
    int L = lane & 15, q = lane >> 4;
    int n0 = (blockIdx.x * 4 + wave) * 16;
    if (n0 >= N) return;  // 16 | N so no partial wave-tiles; no barriers below

    // A-frags: agg row (f32 -> bf16 convert), feature row (pre-converted)
    const float* ar = agg + (long)(n0 + L) * 64;
    bf16x8 Aag[2];
#pragma unroll
    for (int ch = 0; ch < 2; ch++) {
        union { bf16x8 v; __bf16 e[8]; } u;
        const float* p = ar + ch * 32 + q * 8;
#pragma unroll
        for (int j = 0; j < 8; j++) u.e[j] = (__bf16)p[j];
        Aag[ch] = u.v;
    }
    const __bf16* fr = featb + (long)(n0 + L) * 64;
    bf16x8 Aft0 = *(const bf16x8*)(fr + q * 8);
    bf16x8 Aft1 = *(const bf16x8*)(fr + 32 + q * 8);
    bf16x8 Aft[2] = {Aft0, Aft1};

    f32x4 zz = {0.f, 0.f, 0.f, 0.f};
    f32x4 aR[4], aZ[4], aIN[4], aHN[4];
#pragma unroll
    for (int nb = 0; nb < 4; nb++) { aR[nb] = zz; aZ[nb] = zz; aIN[nb] = zz; aHN[nb] = zz; }

    // gates order [r,z,n]: rows g*64.. of W_ih/W_hh. r,z accumulate i+h parts
    // into one accumulator; n keeps i_n and h_n separate (r gates h_n only).
#pragma unroll
    for (int nb = 0; nb < 4; nb++) {
        int row = nb * 16 + L;
#pragma unroll
        for (int ch = 0; ch < 2; ch++) {
            int ko = ch * 32 + q * 8;
            aR[nb]  = MFMA16(Aag[ch], *(const bf16x8*)(wihb + (row)       * 64 + ko), aR[nb], 0, 0, 0);
            aR[nb]  = MFMA16(Aft[ch], *(const bf16x8*)(whhb + (row)       * 64 + ko), aR[nb], 0, 0, 0);
            aZ[nb]  = MFMA16(Aag[ch], *(const bf16x8*)(wihb + (64 + row)  * 64 + ko), aZ[nb], 0, 0, 0);
            aZ[nb]  = MFMA16(Aft[ch], *(const bf16x8*)(whhb + (64 + row)  * 64 + ko), aZ[nb], 0, 0, 0);
            aIN[nb] = MFMA16(Aag[ch], *(const bf16x8*)(wihb + (128 + row) * 64 + ko), aIN[nb], 0, 0, 0);
            aHN[nb] = MFMA16(Aft[ch], *(const bf16x8*)(whhb + (128 + row) * 64 + ko), aHN[nb], 0, 0, 0);
        }
    }

    // elementwise gates in fp32; write h tile (bf16) to per-wave LDS
#pragma unroll
    for (int nb = 0; nb < 4; nb++) {
        int h = nb * 16 + L;
        float br  = bih[h] + bhh[h];
        float bz  = bih[64 + h] + bhh[64 + h];
        float bin = bih[128 + h];
        float bhn = bhh[128 + h];
#pragma unroll
        for (int r = 0; r < 4; r++) {
            int node = n0 + q * 4 + r;
            float rv = sigmoidf_(aR[nb][r] + br);
            float zv = sigmoidf_(aZ[nb][r] + bz);
            float nv = tanhf(aIN[nb][r] + bin + rv * (aHN[nb][r] + bhn));
            float fv = feat[(long)node * 64 + h];  // fp32 blend for accuracy
            float hv = (1.0f - zv) * nv + zv * fv;
            sH[wave][q * 4 + r][h] = (__bf16)hv;
        }
    }
    // same-wave ds_write -> ds_read: LDS ops are in-order per wave; no barrier
    // needed (tile is wave-private, tail waves may have exited already).

    // out = h @ W_out^T + b_out (C=16 -> single n-block, 2 MFMAs)
    bf16x8 Ah0 = *(const bf16x8*)&sH[wave][L][q * 8];
    bf16x8 Ah1 = *(const bf16x8*)&sH[wave][L][32 + q * 8];
    bf16x8 Bo0 = *(const bf16x8*)(woutb + L * 64 + q * 8);
    bf16x8 Bo1 = *(const bf16x8*)(woutb + L * 64 + 32 + q * 8);
    f32x4 o = zz;
    o = MFMA16(Ah0, Bo0, o, 0, 0, 0);
    o = MFMA16(Ah1, Bo1, o, 0, 0, 0);
    float bo = bout[L];
#pragma unroll
    for (int r = 0; r < 4; r++)
        out[(long)(n0 + q * 4 + r) * 16 + L] = o[r] + bo;
}

extern "C" void kernel_launch(void* const* d_in, const int* in_sizes, int n_in,
                              void* d_out, int out_size, void* d_ws, size_t ws_size,
                              hipStream_t stream) {
    const float* features = (const float*)d_in[0];
    const int*   src      = (const int*)d_in[1];
    const int*   dst      = (const int*)d_in[2];
    const unsigned char* etype = (const unsigned char*)d_in[3];  // dtype detected at runtime
    const float* W0   = (const float*)d_in[4];
    const float* b0   = (const float*)d_in[5];
    const float* W1   = (const float*)d_in[6];
    const float* b1   = (const float*)d_in[7];
    const float* Wih  = (const float*)d_in[8];
    const float* Whh  = (const float*)d_in[9];
    const float* bih  = (const float*)d_in[10];
    const float* bhh  = (const float*)d_in[11];
    const float* Wout = (const float*)d_in[12];
    const float* bout = (const float*)d_in[13];
    float* out = (float*)d_out;

    const int N = 100000, E = 1000000;
    char* ws = (char*)d_ws;
    float*  agg   = (float*)ws;                                        // 25.6 MB
    __bf16* featb = (__bf16*)(ws + (size_t)N * 64 * 4);                // 12.8 MB
    __bf16* wb    = (__bf16*)(ws + (size_t)N * 64 * 4 + (size_t)N * 64 * 2);
    int*    flag  = (int*)(ws + (size_t)N * 64 * 4 + (size_t)N * 64 * 2 + 33792 * 2);

    k_det<<<1, 256, 0, stream>>>(etype, flag);
    k_prep<<<(N * 64 / 4 + 255) / 256, 256, 0, stream>>>(features, featb, agg, (long)N * 64);
    k_cvtw<<<132, 256, 0, stream>>>(W0, W1, Wih, Whh, Wout, wb);
    k_edge<<<E / 64, 256, 0, stream>>>(featb, src, dst, etype, flag,
                                       wb, wb + 4096, b0, b1, agg, E);
    k_gru<<<(N + 63) / 64, 256, 0, stream>>>(agg, features, featb,
                                             wb + 8192, wb + 20480, bih, bhh,
                                             wb + 32768, bout, out, N);
}

// Round 3
// 281.886 us; speedup vs baseline: 1.5728x; 1.5728x over previous
//
#include <hip/hip_runtime.h>

// GGNN on MI355X. N=100000, E=1000000, H=M=64, C=16.
// R2 post-mortem: k_edge was atomic-rate bound (64M fp32 atomics, 250 MB HBM
// write-through, all pipes idle); k_det (1 block, serial 64KB scan) ate ~200us.
// R3 rewrite: scatter-add commutes with the per-type linear ->
//   agg[n] = S1[n]@W0^T + c1[n]*b0 + S0[n]@W1^T + c0[n]*b1,
// where S_t[n] = sum of src features over type-t in-edges. Build per-dst edge
// lists (CAP=48, P(overflow) ~ 6e-12), then one fused kernel: fp32 register
// gather-sum -> 2 MFMA matmuls -> bias -> LDS transpose -> GRU -> head.
// Atomics: 64M -> 1M int slot-grabs. k_det parallelized to 64 blocks.
// ws: [featb bf16 N*64 | entries int N*48 | counts int N | wb bf16 33792 | flag]

typedef __bf16 bf16x8 __attribute__((ext_vector_type(8)));
typedef float  f32x4  __attribute__((ext_vector_type(4)));

#define MFMA16 __builtin_amdgcn_mfma_f32_16x16x32_bf16
#define NN  100000
#define EE  1000000
#define CAP 48

__device__ __forceinline__ float sigmoidf_(float x) {
    return 1.0f / (1.0f + __expf(-x));
}

// ---- zero counts + flag ----
__global__ __launch_bounds__(256) void k_zero(int* __restrict__ counts,
                                              int* __restrict__ flag) {
    int i = blockIdx.x * 256 + threadIdx.x;
    if (i < NN) counts[i] = 0;
    if (i == 0) *flag = 0;
}

// ---- detect edge_types storage: flag=1 if 1-byte (bool/int8), 0 if int32 ----
// 64 blocks x 256 threads scan first 64KB in parallel (R2's 1-block version
// serialized ~200us on one CU).
__global__ __launch_bounds__(256) void k_det(const unsigned char* __restrict__ et,
                                             int* __restrict__ flag) {
    int i = blockIdx.x * 256 + threadIdx.x;  // grid exactly covers 65536
    int found = ((i & 3) != 0 && et[i] != 0) ? 1 : 0;
    if (__any(found) && (threadIdx.x & 63) == 0) atomicOr(flag, 1);
}

// ---- features f32 -> bf16 ----
__global__ __launch_bounds__(256) void k_prep(const float* __restrict__ feat,
                                              __bf16* __restrict__ featb) {
    long i = ((long)blockIdx.x * 256 + threadIdx.x) * 4;
    if (i >= (long)NN * 64) return;
    f32x4 v = *(const f32x4*)(feat + i);
    union { __bf16 e[4]; unsigned long long u; } o;
#pragma unroll
    for (int j = 0; j < 4; j++) o.e[j] = (__bf16)v[j];
    *(unsigned long long*)(featb + i) = o.u;
}

// ---- weights f32 -> bf16: W0[4096] W1[4096] W_ih[12288] W_hh[12288] W_out[1024]
__global__ __launch_bounds__(256) void k_cvtw(const float* __restrict__ w0,
                                              const float* __restrict__ w1,
                                              const float* __restrict__ wih,
                                              const float* __restrict__ whh,
                                              const float* __restrict__ wout,
                                              __bf16* __restrict__ wb) {
    int i = blockIdx.x * 256 + threadIdx.x;
    float v;
    if      (i < 4096)  v = w0[i];
    else if (i < 8192)  v = w1[i - 4096];
    else if (i < 20480) v = wih[i - 8192];
    else if (i < 32768) v = whh[i - 20480];
    else if (i < 33792) v = wout[i - 32768];
    else return;
    wb[i] = (__bf16)v;
}

// ---- build per-dst edge lists: entries[d*CAP+slot] = src | (type<<31) ----
__global__ __launch_bounds__(256) void k_scatter(const int* __restrict__ src,
                                                 const int* __restrict__ dst,
                                                 const unsigned char* __restrict__ etype,
                                                 const int* __restrict__ flag,
                                                 int* __restrict__ counts,
                                                 int* __restrict__ entries) {
    int e = blockIdx.x * 256 + threadIdx.x;
    if (e >= EE) return;
    int eshift = (*flag) ? 0 : 2;  // byte stride: 1 (bool) or 4 (int32, LSB)
    int t = etype[(size_t)e << eshift] ? 1 : 0;
    int d = dst[e];
    int slot = atomicAdd(&counts[d], 1);
    if (slot < CAP) entries[d * CAP + slot] = src[e] | (t << 31);
}

// ---- fused node kernel: gather-sum -> msg matmul -> GRU -> classifier ----
// One wave = 16 nodes. Lane (L=lane&15, q=lane>>4) owns node n0+L's k-chunks
// {q*8.., 32+q*8..} during gather (matches MFMA A-frag layout exactly).
__global__ __launch_bounds__(256) void k_node(const __bf16* __restrict__ featb,
                                              const float* __restrict__ feat,
                                              const int* __restrict__ counts,
                                              const int* __restrict__ entries,
                                              const __bf16* __restrict__ wb,
                                              const float* __restrict__ b0,
                                              const float* __restrict__ b1,
                                              const float* __restrict__ bih,
                                              const float* __restrict__ bhh,
                                              const float* __restrict__ bout,
                                              float* __restrict__ out) {
    __shared__ float  sT[4][16][68];  // per-wave agg tile (D->A transpose)
    __shared__ __bf16 sH[4][16][80];  // per-wave h tile
    int tid  = threadIdx.x;
    int lane = tid & 63, wave = tid >> 6;
    int L = lane & 15, q = lane >> 4;
    int n0 = (blockIdx.x * 4 + wave) * 16;
    if (n0 >= NN) return;  // wave-uniform; no __syncthreads below (wave-private LDS)

    // ---- gather + fp32 sum of src features, split by edge type ----
    int n = n0 + L;
    int cnt = min(counts[n], CAP);
    float sAll[16], s1v[16];
#pragma unroll
    for (int j = 0; j < 16; j++) { sAll[j] = 0.f; s1v[j] = 0.f; }
    int c1 = 0;
    const int* ebase = entries + n * CAP;
    for (int i = 0; i < cnt; i++) {
        int ent = ebase[i];
        int s = ent & 0x7fffffff;
        int t = ((unsigned)ent) >> 31;
        const __bf16* row = featb + (long)s * 64;
        bf16x8 a = *(const bf16x8*)(row + q * 8);
        bf16x8 b = *(const bf16x8*)(row + 32 + q * 8);
        c1 += t;
#pragma unroll
        for (int j = 0; j < 8; j++) { sAll[j] += (float)a[j]; sAll[8 + j] += (float)b[j]; }
        if (t) {
#pragma unroll
            for (int j = 0; j < 8; j++) { s1v[j] += (float)a[j]; s1v[8 + j] += (float)b[j]; }
        }
    }

    // A-frags (bf16) for the two type-sums
    bf16x8 AS0[2], AS1[2];
#pragma unroll
    for (int ch = 0; ch < 2; ch++) {
        union { bf16x8 v; __bf16 e[8]; } u0, u1;
#pragma unroll
        for (int j = 0; j < 8; j++) {
            float v1 = s1v[ch * 8 + j];
            u1.e[j] = (__bf16)v1;
            u0.e[j] = (__bf16)(sAll[ch * 8 + j] - v1);
        }
        AS1[ch] = u1.v;
        AS0[ch] = u0.v;
    }

    // ---- msg matmul: agg-tile = S1@W0^T + S0@W1^T (+ count-weighted biases)
    const __bf16* w0b = wb;
    const __bf16* w1b = wb + 4096;
    f32x4 zz = {0.f, 0.f, 0.f, 0.f};
    f32x4 accM[4];
#pragma unroll
    for (int nb = 0; nb < 4; nb++) accM[nb] = zz;
#pragma unroll
    for (int nb = 0; nb < 4; nb++)
#pragma unroll
        for (int ch = 0; ch < 2; ch++) {
            int off = (nb * 16 + L) * 64 + ch * 32 + q * 8;
            accM[nb] = MFMA16(AS1[ch], *(const bf16x8*)(w0b + off), accM[nb], 0, 0, 0);
            accM[nb] = MFMA16(AS0[ch], *(const bf16x8*)(w1b + off), accM[nb], 0, 0, 0);
        }
    float bs0[4], bs1[4];
#pragma unroll
    for (int nb = 0; nb < 4; nb++) {
        bs0[nb] = b0[nb * 16 + L];
        bs1[nb] = b1[nb * 16 + L];
    }
    // D layout: lane holds (node_local m=q*4+r, dim=nb*16+L). Counts for node
    // m live in lane m (its q'=0 copy) -> shfl.
#pragma unroll
    for (int r = 0; r < 4; r++) {
        int m = q * 4 + r;
        int c1n = __shfl(c1, m);
        int can = __shfl(cnt, m);
        float fc1 = (float)c1n, fc0 = (float)(can - c1n);
#pragma unroll
        for (int nb = 0; nb < 4; nb++)
            sT[wave][m][nb * 16 + L] = accM[nb][r] + fc1 * bs0[nb] + fc0 * bs1[nb];
    }
    // same-wave ds_write -> ds_read: in-order, wave-private; no barrier

    // ---- GRU: input = agg (from sT, fp32 -> bf16 A-frag), hidden = features
    bf16x8 Aag[2], Aft[2];
#pragma unroll
    for (int ch = 0; ch < 2; ch++) {
        union { bf16x8 v; __bf16 e[8]; } u;
#pragma unroll
        for (int j = 0; j < 8; j++) u.e[j] = (__bf16)sT[wave][L][ch * 32 + q * 8 + j];
        Aag[ch] = u.v;
    }
    const __bf16* fr = featb + (long)(n0 + L) * 64;
    Aft[0] = *(const bf16x8*)(fr + q * 8);
    Aft[1] = *(const bf16x8*)(fr + 32 + q * 8);

    const __bf16* wihb  = wb + 8192;
    const __bf16* whhb  = wb + 20480;
    const __bf16* woutb = wb + 32768;
    f32x4 aR[4], aZ[4], aIN[4], aHN[4];
#pragma unroll
    for (int nb = 0; nb < 4; nb++) { aR[nb] = zz; aZ[nb] = zz; aIN[nb] = zz; aHN[nb] = zz; }
#pragma unroll
    for (int nb = 0; nb < 4; nb++) {
        int row = nb * 16 + L;
#pragma unroll
        for (int ch = 0; ch < 2; ch++) {
            int ko = ch * 32 + q * 8;
            aR[nb]  = MFMA16(Aag[ch], *(const bf16x8*)(wihb + (row)       * 64 + ko), aR[nb], 0, 0, 0);
            aR[nb]  = MFMA16(Aft[ch], *(const bf16x8*)(whhb + (row)       * 64 + ko), aR[nb], 0, 0, 0);
            aZ[nb]  = MFMA16(Aag[ch], *(const bf16x8*)(wihb + (64 + row)  * 64 + ko), aZ[nb], 0, 0, 0);
            aZ[nb]  = MFMA16(Aft[ch], *(const bf16x8*)(whhb + (64 + row)  * 64 + ko), aZ[nb], 0, 0, 0);
            aIN[nb] = MFMA16(Aag[ch], *(const bf16x8*)(wihb + (128 + row) * 64 + ko), aIN[nb], 0, 0, 0);
            aHN[nb] = MFMA16(Aft[ch], *(const bf16x8*)(whhb + (128 + row) * 64 + ko), aHN[nb], 0, 0, 0);
        }
    }

    // gates fp32; h tile -> LDS (bf16)
#pragma unroll
    for (int nb = 0; nb < 4; nb++) {
        int h = nb * 16 + L;
        float br  = bih[h] + bhh[h];
        float bz  = bih[64 + h] + bhh[64 + h];
        float bin = bih[128 + h];
        float bhn = bhh[128 + h];
#pragma unroll
        for (int r = 0; r < 4; r++) {
            int node = n0 + q * 4 + r;
            float rv = sigmoidf_(aR[nb][r] + br);
            float zv = sigmoidf_(aZ[nb][r] + bz);
            float nv = tanhf(aIN[nb][r] + bin + rv * (aHN[nb][r] + bhn));
            float fv = feat[(long)node * 64 + h];  // fp32 blend for accuracy
            float hv = (1.0f - zv) * nv + zv * fv;
            sH[wave][q * 4 + r][h] = (__bf16)hv;
        }
    }

    // out = h @ W_out^T + b_out
    bf16x8 Ah0 = *(const bf16x8*)&sH[wave][L][q * 8];
    bf16x8 Ah1 = *(const bf16x8*)&sH[wave][L][32 + q * 8];
    bf16x8 Bo0 = *(const bf16x8*)(woutb + L * 64 + q * 8);
    bf16x8 Bo1 = *(const bf16x8*)(woutb + L * 64 + 32 + q * 8);
    f32x4 o = zz;
    o = MFMA16(Ah0, Bo0, o, 0, 0, 0);
    o = MFMA16(Ah1, Bo1, o, 0, 0, 0);
    float bo = bout[L];
#pragma unroll
    for (int r = 0; r < 4; r++)
        out[(long)(n0 + q * 4 + r) * 16 + L] = o[r] + bo;
}

extern "C" void kernel_launch(void* const* d_in, const int* in_sizes, int n_in,
                              void* d_out, int out_size, void* d_ws, size_t ws_size,
                              hipStream_t stream) {
    const float* features = (const float*)d_in[0];
    const int*   src      = (const int*)d_in[1];
    const int*   dst      = (const int*)d_in[2];
    const unsigned char* etype = (const unsigned char*)d_in[3];
    const float* W0   = (const float*)d_in[4];
    const float* b0   = (const float*)d_in[5];
    const float* W1   = (const float*)d_in[6];
    const float* b1   = (const float*)d_in[7];
    const float* Wih  = (const float*)d_in[8];
    const float* Whh  = (const float*)d_in[9];
    const float* bih  = (const float*)d_in[10];
    const float* bhh  = (const float*)d_in[11];
    const float* Wout = (const float*)d_in[12];
    const float* bout = (const float*)d_in[13];
    float* out = (float*)d_out;

    char* ws = (char*)d_ws;
    __bf16* featb   = (__bf16*)ws;                                   // 12.8 MB
    int*    entries = (int*)(ws + (size_t)NN * 64 * 2);              // 19.2 MB
    int*    counts  = (int*)(ws + (size_t)NN * 64 * 2 + (size_t)NN * CAP * 4);
    __bf16* wb      = (__bf16*)((char*)counts + (size_t)NN * 4);
    int*    flag    = (int*)((char*)wb + 33792 * 2);

    k_zero<<<(NN + 255) / 256, 256, 0, stream>>>(counts, flag);
    k_det<<<64, 256, 0, stream>>>(etype, flag);
    k_prep<<<(NN * 64 / 4) / 256, 256, 0, stream>>>(features, featb);
    k_cvtw<<<132, 256, 0, stream>>>(W0, W1, Wih, Whh, Wout, wb);
    k_scatter<<<(EE + 255) / 256, 256, 0, stream>>>(src, dst, etype, flag,
                                                    counts, entries);
    k_node<<<(NN + 63) / 64, 256, 0, stream>>>(featb, features, counts, entries,
                                               wb, b0, b1, bih, bhh, bout, out);
}